// Round 10
// baseline (245.738 us; speedup 1.0000x reference)
//
#include <hip/hip_runtime.h>
#include <stdint.h>

#define KNBR 16

typedef float f32x4 __attribute__((ext_vector_type(4)));
typedef float f32x2 __attribute__((ext_vector_type(2)));
typedef __bf16 bf16x8 __attribute__((ext_vector_type(8)));

union ABFrag { uint4 u; bf16x8 v; };

__device__ __forceinline__ uint32_t bf16_rne(float x) {
    uint32_t u = __float_as_uint(x);
    return (u + 0x7fffu + ((u >> 16) & 1u)) >> 16;
}

// searchsorted(BOUNDARIES=[1,2,4,8,16,32,64,128], d) = clamp(exp + (mant!=0), 0, 8)
__device__ __forceinline__ uint32_t bucket_of(float d) {
    uint32_t u = __float_as_uint(d);
    int e = (int)((u >> 23) & 0xff) - 127;
    int b = e + ((u & 0x7fffffu) != 0 ? 1 : 0);
    return (uint32_t)min(max(b, 0), 8);
}

// ---------- prep (one dispatch): cvt tables + pack W ----------
__global__ void k_prep(const float* __restrict__ src, uint32_t* __restrict__ ebf,
                       uint32_t* __restrict__ e8, int n_dwords,
                       const float* __restrict__ Ws, const float* __restrict__ Wn,
                       uint16_t* __restrict__ Bp) {
    if (blockIdx.x < 2048) {
        int i = blockIdx.x * blockDim.x + threadIdx.x;
        int stride = 2048 * blockDim.x;
        for (; i < n_dwords; i += stride) {
            float4 v = ((const float4*)src)[i];
            ebf[2 * i]     = bf16_rne(v.x) | (bf16_rne(v.y) << 16);
            ebf[2 * i + 1] = bf16_rne(v.z) | (bf16_rne(v.w) << 16);
            uint32_t p = 0;
            p = __builtin_amdgcn_cvt_pk_fp8_f32(v.x, v.y, p, false);
            p = __builtin_amdgcn_cvt_pk_fp8_f32(v.z, v.w, p, true);
            e8[i] = p;
        }
    } else {
        int o = (blockIdx.x - 2048) * blockDim.x + threadIdx.x;
        if (o >= 8 * 8 * 64 * 8) return;
        int i = o & 7, lane = (o >> 3) & 63, nt = (o >> 9) & 7, ks = o >> 12;
        int r = ks * 32 + (lane >> 4) * 8 + i;
        int c = nt * 16 + (lane & 15);
        float v = (r < 128) ? Ws[r * 128 + c] : Wn[(r - 128) * 128 + c];
        Bp[o] = (uint16_t)bf16_rne(v);
    }
}

// ---------- ablation family of the R5 fused kernel (126 us reference) ----------
// MODE 0: full   (writes correct out; launched LAST)
// MODE 1: index translate + gather + LDS stage only (no MFMA, no out)
// MODE 2: MFMA + epilogue only (reads whatever LDS holds; out overwritten by MODE 0 later)
// MODE 3: index translate only
#define A_STRIDE 132
template <int MODE>
__global__ __launch_bounds__(1024, 4) void k_abl(
    const int* __restrict__ node_ids, const int* __restrict__ nbr_idx,
    const float* __restrict__ nbr_dist,
    const uint32_t* __restrict__ emb_bf, const uint16_t* __restrict__ emb8,
    const float* __restrict__ dist_table, const float* __restrict__ bias,
    const uint32_t* __restrict__ Bp, float* __restrict__ out, int ntiles)
{
    __shared__ uint32_t As[16 * 16 * A_STRIDE];
    __shared__ float bsh[128];
    if (threadIdx.x < 128) bsh[threadIdx.x] = bias[threadIdx.x];
    __syncthreads();

    const int lane = threadIdx.x & 63;
    const int w = threadIdx.x >> 6;
    const int l_hi = lane >> 4;
    const int l_lo = lane & 15;
    uint32_t* Aw = As + w * (16 * A_STRIDE);
    float* Fw = (float*)(As) + w * (16 * A_STRIDE);

    float2 dreg[9];
    #pragma unroll
    for (int b = 0; b < 9; ++b)
        dreg[b] = *(const float2*)(dist_table + b * 128 + 2 * lane);

    const int wid = blockIdx.x * 16 + w;
    const int nwaves = gridDim.x * 16;

    for (int tile = wid; tile < ntiles; tile += nwaves) {
        if (MODE == 0 || MODE == 1 || MODE == 3) {
            // ---- phase A: translate 256 neighbor ids (4 per lane) ----
            int4 nb = *(const int4*)(nbr_idx + (size_t)tile * 256 + lane * 4);
            float4 dd = *(const float4*)(nbr_dist + (size_t)tile * 256 + lane * 4);
            uint32_t ea[4];
            ea[0] = ((uint32_t)node_ids[nb.x] & 0xFFFFFFu) | (bucket_of(dd.x) << 24);
            ea[1] = ((uint32_t)node_ids[nb.y] & 0xFFFFFFu) | (bucket_of(dd.y) << 24);
            ea[2] = ((uint32_t)node_ids[nb.z] & 0xFFFFFFu) | (bucket_of(dd.z) << 24);
            ea[3] = ((uint32_t)node_ids[nb.w] & 0xFFFFFFu) | (bucket_of(dd.w) << 24);
            uint32_t selfv = (uint32_t)node_ids[(size_t)tile * 16 + (lane & 15)];

            if (MODE == 3) {
                asm volatile("" :: "v"(ea[0]), "v"(ea[1]), "v"(ea[2]), "v"(ea[3]), "v"(selfv));
                continue;
            }

            // ---- phase B: per node j, wave-uniform row gathers, scalar histogram ----
            #pragma unroll
            for (int j = 0; j < 16; ++j) {
                const int sw = (j & 7) << 2;
                const uint32_t sid = (uint32_t)__builtin_amdgcn_readlane((int)selfv, j);
                const uint32_t hp = emb_bf[(size_t)sid * 64 + lane];
                uint64_t cnt = 0;
                uint32_t p[KNBR];
                #pragma unroll
                for (int k = 0; k < KNBR; ++k) {
                    const uint32_t ew = (uint32_t)__builtin_amdgcn_readlane((int)ea[k & 3], 4 * j + (k >> 2));
                    cnt += 1ull << (5 * (ew >> 24));
                    p[k] = (uint32_t)emb8[(size_t)(ew & 0xFFFFFFu) * 64 + lane];
                }
                float ax = 0.f, ay = 0.f;
                #pragma unroll
                for (int k = 0; k < KNBR; ++k) {
                    f32x2 d = __builtin_amdgcn_cvt_pk_f32_fp8(p[k], false);
                    ax += d.x; ay += d.y;
                }
                #pragma unroll
                for (int b = 0; b < 9; ++b) {
                    const float fb = (float)(uint32_t)((cnt >> (5 * b)) & 31u);
                    ax += fb * dreg[b].x; ay += fb * dreg[b].y;
                }
                ax *= 0.0625f; ay *= 0.0625f;
                Aw[j * A_STRIDE + (lane ^ sw)] = hp;
                Aw[j * A_STRIDE + 64 + (lane ^ sw)] = bf16_rne(ax) | (bf16_rne(ay) << 16);
            }
            if (MODE == 1) continue;
        }

        if (MODE == 0 || MODE == 2) {
            asm volatile("s_waitcnt lgkmcnt(0)" ::: "memory");

            f32x4 acc[8];
            #pragma unroll
            for (int t = 0; t < 8; ++t) acc[t] = (f32x4){0.f, 0.f, 0.f, 0.f};
            #pragma unroll
            for (int ks = 0; ks < 8; ++ks) {
                ABFrag a;
                a.u = *(const uint4*)(Aw + l_lo * A_STRIDE + ((ks * 16 + l_hi * 4) ^ ((l_lo & 7) << 2)));
                #pragma unroll
                for (int nt = 0; nt < 8; ++nt) {
                    ABFrag b;
                    b.u = ((const uint4*)Bp)[(ks * 8 + nt) * 64 + lane];
                    acc[nt] = __builtin_amdgcn_mfma_f32_16x16x32_bf16(a.v, b.v, acc[nt], 0, 0, 0);
                }
            }
            #pragma unroll
            for (int nt = 0; nt < 8; ++nt) {
                const int col = nt * 16 + l_lo;
                const float bv = bsh[col];
                #pragma unroll
                for (int r = 0; r < 4; ++r) {
                    float v = acc[nt][r] + bv;
                    Fw[(l_hi * 4 + r) * A_STRIDE + col] = v > 0.f ? v : 0.f;
                }
            }
            float* dst = out + (size_t)tile * 2048;
            #pragma unroll
            for (int it = 0; it < 8; ++it) {
                const int f = it * 256 + lane * 4;
                const int r = f >> 7, c = f & 127;
                float4 v = *(const float4*)(Fw + r * A_STRIDE + c);
                *(float4*)(dst + f) = v;
            }
        }
    }

    if (MODE == 1) {
        // dynamic reads block dead-store elimination of the As staging writes
        asm volatile("" :: "v"(As[threadIdx.x]), "v"(As[threadIdx.x + 16384]));
    }
}

// ---------- safety fallback (tiny ws / tail nodes) ----------
__global__ void k_naive(const int* __restrict__ node_ids, const int* __restrict__ nbr_idx,
                        const float* __restrict__ nbr_dist, const float* __restrict__ emb,
                        const float* __restrict__ dt, const float* __restrict__ Ws,
                        const float* __restrict__ Wn, const float* __restrict__ bias,
                        float* __restrict__ out, int base) {
    __shared__ float h[128], ag[128];
    const int nd = base + blockIdx.x;
    const int t = threadIdx.x;
    const int nid = node_ids[nd];
    float hv = emb[(size_t)nid * 128 + t];
    float a = 0.f;
    for (int k = 0; k < KNBR; ++k) {
        int sn = node_ids[nbr_idx[(size_t)nd * KNBR + k]];
        int bkt = (int)bucket_of(nbr_dist[(size_t)nd * KNBR + k]);
        a += emb[(size_t)sn * 128 + t] + dt[bkt * 128 + t];
    }
    h[t] = hv; ag[t] = a * 0.0625f;
    __syncthreads();
    float s = bias[t];
    for (int d = 0; d < 128; ++d) s += h[d] * Ws[d * 128 + t] + ag[d] * Wn[d * 128 + t];
    out[(size_t)nd * 128 + t] = s > 0.f ? s : 0.f;
}

extern "C" void kernel_launch(void* const* d_in, const int* in_sizes, int n_in,
                              void* d_out, int out_size, void* d_ws, size_t ws_size,
                              hipStream_t stream) {
    const int* node_ids   = (const int*)d_in[0];
    const int* nbr_idx    = (const int*)d_in[1];
    const float* nbr_dist = (const float*)d_in[2];
    const float* emb      = (const float*)d_in[3];
    const float* dist_tab = (const float*)d_in[4];
    const float* Ws       = (const float*)d_in[5];
    const float* Wn       = (const float*)d_in[6];
    const float* bias     = (const float*)d_in[7];
    float* out = (float*)d_out;
    const int n = in_sizes[0];
    const int in_dim = in_sizes[3] / 128;

    const size_t offEbf = 65536;               // after 64KB packed-W
    const size_t offE8  = offEbf + (size_t)in_dim * 256;
    const size_t needT  = offE8 + (size_t)in_dim * 128;

    if (ws_size < needT) {
        if (n > 0)
            k_naive<<<n, 128, 0, stream>>>(node_ids, nbr_idx, nbr_dist, emb, dist_tab, Ws, Wn, bias, out, 0);
        return;
    }
    uint16_t* Bp   = (uint16_t*)d_ws;
    uint32_t* ebf  = (uint32_t*)((char*)d_ws + offEbf);
    uint32_t* e8   = (uint32_t*)((char*)d_ws + offE8);

    k_prep<<<2176, 256, 0, stream>>>(emb, ebf, e8, in_dim * 32, Ws, Wn, Bp);

    const int ntiles = n >> 4;
    const int rem = n & 15;

    if (ntiles > 0) {
        // diagnostic variants (outputs unused / overwritten); full kernel runs LAST
        k_abl<3><<<256, 1024, 0, stream>>>(node_ids, nbr_idx, nbr_dist, ebf, (const uint16_t*)e8,
                                           dist_tab, bias, (const uint32_t*)Bp, out, ntiles);
        k_abl<1><<<256, 1024, 0, stream>>>(node_ids, nbr_idx, nbr_dist, ebf, (const uint16_t*)e8,
                                           dist_tab, bias, (const uint32_t*)Bp, out, ntiles);
        k_abl<2><<<256, 1024, 0, stream>>>(node_ids, nbr_idx, nbr_dist, ebf, (const uint16_t*)e8,
                                           dist_tab, bias, (const uint32_t*)Bp, out, ntiles);
        k_abl<0><<<256, 1024, 0, stream>>>(node_ids, nbr_idx, nbr_dist, ebf, (const uint16_t*)e8,
                                           dist_tab, bias, (const uint32_t*)Bp, out, ntiles);
    }
    if (rem > 0)
        k_naive<<<rem, 128, 0, stream>>>(node_ids, nbr_idx, nbr_dist, emb, dist_tab, Ws, Wn, bias, out, ntiles << 4);
}

// Round 11
// 142.164 us; speedup vs baseline: 1.7285x; 1.7285x over previous
//
#include <hip/hip_runtime.h>
#include <stdint.h>

#define KNBR 16

typedef float f32x4 __attribute__((ext_vector_type(4)));
typedef float f32x2 __attribute__((ext_vector_type(2)));
typedef __bf16 bf16x8 __attribute__((ext_vector_type(8)));

union ABFrag { uint4 u; bf16x8 v; };

__device__ __forceinline__ uint32_t bf16_rne(float x) {
    uint32_t u = __float_as_uint(x);
    return (u + 0x7fffu + ((u >> 16) & 1u)) >> 16;
}

// searchsorted(BOUNDARIES=[1,2,4,8,16,32,64,128], d) = clamp(exp + (mant!=0), 0, 8)
__device__ __forceinline__ uint32_t bucket_of(float d) {
    uint32_t u = __float_as_uint(d);
    int e = (int)((u >> 23) & 0xff) - 127;
    int b = e + ((u & 0x7fffffu) != 0 ? 1 : 0);
    return (uint32_t)min(max(b, 0), 8);
}

// ---------- prep (one dispatch): cvt tables + pack W ----------
__global__ void k_prep(const float* __restrict__ src, uint32_t* __restrict__ ebf,
                       uint32_t* __restrict__ e8, int n_dwords,
                       const float* __restrict__ Ws, const float* __restrict__ Wn,
                       uint16_t* __restrict__ Bp) {
    if (blockIdx.x < 2048) {
        int i = blockIdx.x * blockDim.x + threadIdx.x;
        int stride = 2048 * blockDim.x;
        for (; i < n_dwords; i += stride) {
            float4 v = ((const float4*)src)[i];
            ebf[2 * i]     = bf16_rne(v.x) | (bf16_rne(v.y) << 16);
            ebf[2 * i + 1] = bf16_rne(v.z) | (bf16_rne(v.w) << 16);
            uint32_t p = 0;
            p = __builtin_amdgcn_cvt_pk_fp8_f32(v.x, v.y, p, false);
            p = __builtin_amdgcn_cvt_pk_fp8_f32(v.z, v.w, p, true);
            e8[i] = p;
        }
    } else {
        int o = (blockIdx.x - 2048) * blockDim.x + threadIdx.x;
        if (o >= 8 * 8 * 64 * 8) return;
        int i = o & 7, lane = (o >> 3) & 63, nt = (o >> 9) & 7, ks = o >> 12;
        int r = ks * 32 + (lane >> 4) * 8 + i;
        int c = nt * 16 + (lane & 15);
        float v = (r < 128) ? Ws[r * 128 + c] : Wn[(r - 128) * 128 + c];
        Bp[o] = (uint16_t)bf16_rne(v);
    }
}

// ---------- fused: k_gather-style paired-issue gather + MFMA ----------
#define A_STRIDE 132
__global__ __launch_bounds__(1024, 4) void k_fused(
    const int* __restrict__ node_ids, const int* __restrict__ nbr_idx,
    const float* __restrict__ nbr_dist,
    const uint32_t* __restrict__ emb_bf, const uint16_t* __restrict__ emb8,
    const float* __restrict__ dist_table, const float* __restrict__ bias,
    const uint32_t* __restrict__ Bp, float* __restrict__ out, int ntiles)
{
    __shared__ uint32_t As[16 * 16 * A_STRIDE];   // 135168 B — only LDS (1 block/CU, 16 waves)

    const int lane = threadIdx.x & 63;
    const int w = threadIdx.x >> 6;
    const int l_hi = lane >> 4;
    const int l_lo = lane & 15;
    uint32_t* Aw = As + w * (16 * A_STRIDE);
    float* Fw = (float*)(As) + w * (16 * A_STRIDE);

    // dist table + bias in regs
    float2 dreg[9];
    #pragma unroll
    for (int b = 0; b < 9; ++b)
        dreg[b] = *(const float2*)(dist_table + b * 128 + 2 * lane);
    float breg[8];
    #pragma unroll
    for (int nt = 0; nt < 8; ++nt) breg[nt] = bias[nt * 16 + l_lo];

    const int wid = blockIdx.x * 16 + w;
    const int nwaves = gridDim.x * 16;

    for (int tile = wid; tile < ntiles; tile += nwaves) {
        // ---- phase A: translate 256 neighbor ids (4 per lane) ----
        int4 nb = *(const int4*)(nbr_idx + (size_t)tile * 256 + lane * 4);
        float4 dd = *(const float4*)(nbr_dist + (size_t)tile * 256 + lane * 4);
        uint32_t ea[4];
        ea[0] = ((uint32_t)node_ids[nb.x] & 0xFFFFFFu) | (bucket_of(dd.x) << 24);
        ea[1] = ((uint32_t)node_ids[nb.y] & 0xFFFFFFu) | (bucket_of(dd.y) << 24);
        ea[2] = ((uint32_t)node_ids[nb.z] & 0xFFFFFFu) | (bucket_of(dd.z) << 24);
        ea[3] = ((uint32_t)node_ids[nb.w] & 0xFFFFFFu) | (bucket_of(dd.w) << 24);
        uint32_t selfv = (uint32_t)node_ids[(size_t)tile * 16 + (lane & 15)];

        // ---- phase B: j-pairs, batch-issue both then consume both (k_gather's proven shape) ----
        #pragma unroll 1
        for (int jp = 0; jp < 8; ++jp) {
            const int j0 = jp * 2, j1 = jp * 2 + 1;

            const uint32_t sid0 = (uint32_t)__builtin_amdgcn_readlane((int)selfv, j0);
            const uint32_t sid1 = (uint32_t)__builtin_amdgcn_readlane((int)selfv, j1);
            const uint32_t h0 = emb_bf[(size_t)sid0 * 64 + lane];
            const uint32_t h1 = emb_bf[(size_t)sid1 * 64 + lane];

            uint32_t p0[KNBR], p1[KNBR];
            uint64_t c0 = 0, c1 = 0;
            #pragma unroll
            for (int k = 0; k < KNBR; ++k) {
                const uint32_t e0 = (uint32_t)__builtin_amdgcn_readlane((int)ea[k & 3], 4 * j0 + (k >> 2));
                const uint32_t e1 = (uint32_t)__builtin_amdgcn_readlane((int)ea[k & 3], 4 * j1 + (k >> 2));
                c0 += 1ull << (5 * (e0 >> 24));
                c1 += 1ull << (5 * (e1 >> 24));
                p0[k] = (uint32_t)emb8[(size_t)(e0 & 0xFFFFFFu) * 64 + lane];
                p1[k] = (uint32_t)emb8[(size_t)(e1 & 0xFFFFFFu) * 64 + lane];
            }

            float ax0 = 0.f, ay0 = 0.f, ax1 = 0.f, ay1 = 0.f;
            #pragma unroll
            for (int k = 0; k < KNBR; ++k) {
                f32x2 d0 = __builtin_amdgcn_cvt_pk_f32_fp8(p0[k], false);
                f32x2 d1 = __builtin_amdgcn_cvt_pk_f32_fp8(p1[k], false);
                ax0 += d0.x; ay0 += d0.y;
                ax1 += d1.x; ay1 += d1.y;
            }
            #pragma unroll
            for (int b = 0; b < 9; ++b) {
                const float f0 = (float)(uint32_t)((c0 >> (5 * b)) & 31u);
                const float f1 = (float)(uint32_t)((c1 >> (5 * b)) & 31u);
                ax0 += f0 * dreg[b].x; ay0 += f0 * dreg[b].y;
                ax1 += f1 * dreg[b].x; ay1 += f1 * dreg[b].y;
            }
            ax0 *= 0.0625f; ay0 *= 0.0625f; ax1 *= 0.0625f; ay1 *= 0.0625f;

            const int sw0 = (j0 & 7) << 2, sw1 = (j1 & 7) << 2;
            Aw[j0 * A_STRIDE + (lane ^ sw0)] = h0;
            Aw[j0 * A_STRIDE + 64 + (lane ^ sw0)] = bf16_rne(ax0) | (bf16_rne(ay0) << 16);
            Aw[j1 * A_STRIDE + (lane ^ sw1)] = h1;
            Aw[j1 * A_STRIDE + 64 + (lane ^ sw1)] = bf16_rne(ax1) | (bf16_rne(ay1) << 16);
        }

        asm volatile("s_waitcnt lgkmcnt(0)" ::: "memory");

        // ---- MFMA phase: 16 rows x 128 cols, K=256 ----
        f32x4 acc[8];
        #pragma unroll
        for (int t = 0; t < 8; ++t) acc[t] = (f32x4){0.f, 0.f, 0.f, 0.f};
        #pragma unroll
        for (int ks = 0; ks < 8; ++ks) {
            ABFrag a;
            a.u = *(const uint4*)(Aw + l_lo * A_STRIDE + ((ks * 16 + l_hi * 4) ^ ((l_lo & 7) << 2)));
            #pragma unroll
            for (int nt = 0; nt < 8; ++nt) {
                ABFrag b;   // packed weights, L2-hot
                b.u = ((const uint4*)Bp)[(ks * 8 + nt) * 64 + lane];
                acc[nt] = __builtin_amdgcn_mfma_f32_16x16x32_bf16(a.v, b.v, acc[nt], 0, 0, 0);
            }
        }

        // ---- epilogue: bias+relu -> LDS transpose -> full-line stores ----
        #pragma unroll
        for (int nt = 0; nt < 8; ++nt) {
            const int col = nt * 16 + l_lo;
            #pragma unroll
            for (int r = 0; r < 4; ++r) {
                float v = acc[nt][r] + breg[nt];
                Fw[(l_hi * 4 + r) * A_STRIDE + col] = v > 0.f ? v : 0.f;
            }
        }
        float* dst = out + (size_t)tile * 2048;
        #pragma unroll
        for (int it = 0; it < 8; ++it) {
            const int f = it * 256 + lane * 4;
            const int r = f >> 7, c = f & 127;
            float4 v = *(const float4*)(Fw + r * A_STRIDE + c);
            *(float4*)(dst + f) = v;
        }
    }
}

// ---------- safety fallback (tiny ws / tail nodes) ----------
__global__ void k_naive(const int* __restrict__ node_ids, const int* __restrict__ nbr_idx,
                        const float* __restrict__ nbr_dist, const float* __restrict__ emb,
                        const float* __restrict__ dt, const float* __restrict__ Ws,
                        const float* __restrict__ Wn, const float* __restrict__ bias,
                        float* __restrict__ out, int base) {
    __shared__ float h[128], ag[128];
    const int nd = base + blockIdx.x;
    const int t = threadIdx.x;
    const int nid = node_ids[nd];
    float hv = emb[(size_t)nid * 128 + t];
    float a = 0.f;
    for (int k = 0; k < KNBR; ++k) {
        int sn = node_ids[nbr_idx[(size_t)nd * KNBR + k]];
        int bkt = (int)bucket_of(nbr_dist[(size_t)nd * KNBR + k]);
        a += emb[(size_t)sn * 128 + t] + dt[bkt * 128 + t];
    }
    h[t] = hv; ag[t] = a * 0.0625f;
    __syncthreads();
    float s = bias[t];
    for (int d = 0; d < 128; ++d) s += h[d] * Ws[d * 128 + t] + ag[d] * Wn[d * 128 + t];
    out[(size_t)nd * 128 + t] = s > 0.f ? s : 0.f;
}

extern "C" void kernel_launch(void* const* d_in, const int* in_sizes, int n_in,
                              void* d_out, int out_size, void* d_ws, size_t ws_size,
                              hipStream_t stream) {
    const int* node_ids   = (const int*)d_in[0];
    const int* nbr_idx    = (const int*)d_in[1];
    const float* nbr_dist = (const float*)d_in[2];
    const float* emb      = (const float*)d_in[3];
    const float* dist_tab = (const float*)d_in[4];
    const float* Ws       = (const float*)d_in[5];
    const float* Wn       = (const float*)d_in[6];
    const float* bias     = (const float*)d_in[7];
    float* out = (float*)d_out;
    const int n = in_sizes[0];
    const int in_dim = in_sizes[3] / 128;

    const size_t offEbf = 65536;               // after 64KB packed-W
    const size_t offE8  = offEbf + (size_t)in_dim * 256;
    const size_t needT  = offE8 + (size_t)in_dim * 128;

    if (ws_size < needT) {
        if (n > 0)
            k_naive<<<n, 128, 0, stream>>>(node_ids, nbr_idx, nbr_dist, emb, dist_tab, Ws, Wn, bias, out, 0);
        return;
    }
    uint16_t* Bp   = (uint16_t*)d_ws;
    uint32_t* ebf  = (uint32_t*)((char*)d_ws + offEbf);
    uint32_t* e8   = (uint32_t*)((char*)d_ws + offE8);

    k_prep<<<2176, 256, 0, stream>>>(emb, ebf, e8, in_dim * 32, Ws, Wn, Bp);

    const int ntiles = n >> 4;
    const int rem = n & 15;

    if (ntiles > 0)
        k_fused<<<256, 1024, 0, stream>>>(node_ids, nbr_idx, nbr_dist, ebf, (const uint16_t*)e8,
                                          dist_tab, bias, (const uint32_t*)Bp, out, ntiles);
    if (rem > 0)
        k_naive<<<rem, 128, 0, stream>>>(node_ids, nbr_idx, nbr_dist, emb, dist_tab, Ws, Wn, bias, out, ntiles << 4);
}

// Round 12
// 94.021 us; speedup vs baseline: 2.6136x; 1.5120x over previous
//
#include <hip/hip_runtime.h>
#include <stdint.h>

#define KNBR 16
#define STAGE_D 6

typedef float f32x4 __attribute__((ext_vector_type(4)));
typedef float f32x2 __attribute__((ext_vector_type(2)));
typedef __bf16 bf16x8 __attribute__((ext_vector_type(8)));

union ABFrag { uint4 u; bf16x8 v; };

__device__ __forceinline__ uint32_t bf16_rne(float x) {
    uint32_t u = __float_as_uint(x);
    return (u + 0x7fffu + ((u >> 16) & 1u)) >> 16;
}

// searchsorted(BOUNDARIES=[1,2,4,8,16,32,64,128], d) = clamp(exp + (mant!=0), 0, 8)
__device__ __forceinline__ uint32_t bucket_of(float d) {
    uint32_t u = __float_as_uint(d);
    int e = (int)((u >> 23) & 0xff) - 127;
    int b = e + ((u & 0x7fffffu) != 0 ? 1 : 0);
    return (uint32_t)min(max(b, 0), 8);
}

#define GLD(gsrc, ldst)                                                          \
    __builtin_amdgcn_global_load_lds(                                            \
        (const __attribute__((address_space(1))) void*)(gsrc),                   \
        (__attribute__((address_space(3))) void*)(ldst), 4, 0, 0)

// ---------- prep (one dispatch): cvt tables + pack W ----------
__global__ void k_prep(const float* __restrict__ src, uint32_t* __restrict__ ebf,
                       uint32_t* __restrict__ e8, int n_dwords,
                       const float* __restrict__ Ws, const float* __restrict__ Wn,
                       uint16_t* __restrict__ Bp) {
    if (blockIdx.x < 2048) {
        int i = blockIdx.x * blockDim.x + threadIdx.x;
        int stride = 2048 * blockDim.x;
        for (; i < n_dwords; i += stride) {
            float4 v = ((const float4*)src)[i];
            ebf[2 * i]     = bf16_rne(v.x) | (bf16_rne(v.y) << 16);
            ebf[2 * i + 1] = bf16_rne(v.z) | (bf16_rne(v.w) << 16);
            uint32_t p = 0;
            p = __builtin_amdgcn_cvt_pk_fp8_f32(v.x, v.y, p, false);
            p = __builtin_amdgcn_cvt_pk_fp8_f32(v.z, v.w, p, true);
            e8[i] = p;
        }
    } else {
        int o = (blockIdx.x - 2048) * blockDim.x + threadIdx.x;
        if (o >= 8 * 8 * 64 * 8) return;
        int i = o & 7, lane = (o >> 3) & 63, nt = (o >> 9) & 7, ks = o >> 12;
        int r = ks * 32 + (lane >> 4) * 8 + i;
        int c = nt * 16 + (lane & 15);
        float v = (r < 128) ? Ws[r * 128 + c] : Wn[(r - 128) * 128 + c];
        Bp[o] = (uint16_t)bf16_rne(v);
    }
}

// ---------- fused: global_load_lds D-deep gather pipeline + MFMA ----------
// LDS per block (4 waves): A 4x8KB + stage 4x12KB = 80KB -> exactly 2 blocks/CU.
__global__ __launch_bounds__(256, 2) void k_fused(
    const int* __restrict__ node_ids, const int* __restrict__ nbr_idx,
    const float* __restrict__ nbr_dist,
    const uint32_t* __restrict__ emb_bf, const uint16_t* __restrict__ emb8,
    const float* __restrict__ dist_table, const float* __restrict__ bias,
    const uint32_t* __restrict__ Bp, float* __restrict__ out, int ntiles)
{
    __shared__ uint32_t As[4 * 16 * 128];       // 32 KB: per-wave 16 rows x 128 dwords (swizzled)
    __shared__ uint32_t Ss[4 * STAGE_D * 512];  // 48 KB: per-wave 6 slots x 2KB fp8 stage

    const int lane = threadIdx.x & 63;
    const int w = threadIdx.x >> 6;
    const int l_hi = lane >> 4;
    const int l_lo = lane & 15;
    uint32_t* Aw = As + w * 2048;
    uint32_t* Sw = Ss + w * (STAGE_D * 512);
    float* Fw = (float*)Aw;

    const int tile = blockIdx.x * 4 + w;
    if (tile >= ntiles) return;

    // dist table + bias in regs
    float2 dreg[9];
    #pragma unroll
    for (int b = 0; b < 9; ++b)
        dreg[b] = *(const float2*)(dist_table + b * 128 + 2 * lane);
    float breg[8];
    #pragma unroll
    for (int nt = 0; nt < 8; ++nt) breg[nt] = bias[nt * 16 + l_lo];

    // ---- phase A: translate 256 neighbor ids (4 per lane) ----
    int4 nb = *(const int4*)(nbr_idx + (size_t)tile * 256 + lane * 4);
    float4 dd = *(const float4*)(nbr_dist + (size_t)tile * 256 + lane * 4);
    uint32_t ea[4];
    ea[0] = ((uint32_t)node_ids[nb.x] & 0xFFFFFFu) | (bucket_of(dd.x) << 24);
    ea[1] = ((uint32_t)node_ids[nb.y] & 0xFFFFFFu) | (bucket_of(dd.y) << 24);
    ea[2] = ((uint32_t)node_ids[nb.z] & 0xFFFFFFu) | (bucket_of(dd.z) << 24);
    ea[3] = ((uint32_t)node_ids[nb.w] & 0xFFFFFFu) | (bucket_of(dd.w) << 24);
    uint32_t selfv = (uint32_t)node_ids[(size_t)tile * 16 + (lane & 15)];

    // ---- ISSUE(j): 1 self gl_lds (pre-swizzled src -> linear LDS) + 8 nbr-pair gl_lds ----
#define ISSUE(J) do {                                                                     \
        const int sw_ = ((J) & 7) << 2;                                                   \
        const uint32_t sid_ = (uint32_t)__builtin_amdgcn_readlane((int)selfv, (J));       \
        GLD(emb_bf + (size_t)sid_ * 64 + (lane ^ sw_), Aw + (J) * 128);                   \
        uint32_t* sb_ = Sw + ((J) % STAGE_D) * 512;                                       \
        _Pragma("unroll")                                                                 \
        for (int m = 0; m < 8; ++m) {                                                     \
            const int L_ = 4 * (J) + (m >> 1);                                            \
            const uint32_t s0_ = (uint32_t)__builtin_amdgcn_readlane((int)ea[(2*m) & 3], L_) & 0xFFFFFFu;   \
            const uint32_t s1_ = (uint32_t)__builtin_amdgcn_readlane((int)ea[(2*m+1) & 3], L_) & 0xFFFFFFu; \
            const uint32_t sel_ = (lane < 32) ? s0_ : s1_;                                \
            GLD((const uint8_t*)emb8 + (size_t)sel_ * 128 + (lane & 31) * 4, sb_ + m * 64); \
        }                                                                                 \
    } while (0)

    // ---- CONSUME(j, VM): counted vmcnt wait, then LDS consume + agg write ----
#define CONSUME(J, VM) do {                                                               \
        asm volatile("s_waitcnt vmcnt(" #VM ")" ::: "memory");                            \
        const uint16_t* st_ = (const uint16_t*)(Sw + ((J) % STAGE_D) * 512);              \
        float ax = 0.f, ay = 0.f;                                                         \
        uint64_t c_ = 0;                                                                  \
        _Pragma("unroll")                                                                 \
        for (int k = 0; k < KNBR; ++k) {                                                  \
            const uint32_t ew_ = (uint32_t)__builtin_amdgcn_readlane((int)ea[k & 3], 4 * (J) + (k >> 2)); \
            c_ += 1ull << (5 * (ew_ >> 24));                                              \
            const uint32_t pv_ = (uint32_t)st_[k * 64 + lane];                            \
            f32x2 d_ = __builtin_amdgcn_cvt_pk_f32_fp8(pv_, false);                       \
            ax += d_.x; ay += d_.y;                                                       \
        }                                                                                 \
        _Pragma("unroll")                                                                 \
        for (int b = 0; b < 9; ++b) {                                                     \
            const float fb_ = (float)(uint32_t)((c_ >> (5 * b)) & 31u);                   \
            ax += fb_ * dreg[b].x; ay += fb_ * dreg[b].y;                                 \
        }                                                                                 \
        ax *= 0.0625f; ay *= 0.0625f;                                                     \
        const int sw_ = ((J) & 7) << 2;                                                   \
        Aw[(J) * 128 + (64 + (lane ^ sw_))] = bf16_rne(ax) | (bf16_rne(ay) << 16);        \
        __builtin_amdgcn_sched_barrier(0);                                                \
    } while (0)

    // ---- D=6-deep pipeline over the 16 nodes ----
    ISSUE(0); ISSUE(1); ISSUE(2); ISSUE(3); ISSUE(4); ISSUE(5);
    CONSUME(0, 45);  ISSUE(6);
    CONSUME(1, 45);  ISSUE(7);
    CONSUME(2, 45);  ISSUE(8);
    CONSUME(3, 45);  ISSUE(9);
    CONSUME(4, 45);  ISSUE(10);
    CONSUME(5, 45);  ISSUE(11);
    CONSUME(6, 45);  ISSUE(12);
    CONSUME(7, 45);  ISSUE(13);
    CONSUME(8, 45);  ISSUE(14);
    CONSUME(9, 45);  ISSUE(15);
    CONSUME(10, 45);
    CONSUME(11, 36);
    CONSUME(12, 27);
    CONSUME(13, 18);
    CONSUME(14, 9);
    CONSUME(15, 0);
#undef ISSUE
#undef CONSUME

    asm volatile("s_waitcnt vmcnt(0) lgkmcnt(0)" ::: "memory");
    __builtin_amdgcn_sched_barrier(0);

    // ---- MFMA: 16 rows x 128 cols, K=256; A-frags swizzled ds_read_b128 ----
    f32x4 acc[8];
    #pragma unroll
    for (int t = 0; t < 8; ++t) acc[t] = (f32x4){0.f, 0.f, 0.f, 0.f};
    #pragma unroll
    for (int ks = 0; ks < 8; ++ks) {
        ABFrag a;   // A[row=l_lo][k = ks*32 + l_hi*8 + 0..7]
        a.u = *(const uint4*)(Aw + l_lo * 128 + ((ks * 16 + l_hi * 4) ^ ((l_lo & 7) << 2)));
        #pragma unroll
        for (int nt = 0; nt < 8; ++nt) {
            ABFrag b;   // packed weights, L2-hot
            b.u = ((const uint4*)Bp)[(ks * 8 + nt) * 64 + lane];
            acc[nt] = __builtin_amdgcn_mfma_f32_16x16x32_bf16(a.v, b.v, acc[nt], 0, 0, 0);
        }
    }

    // ---- epilogue: bias+relu -> swizzled LDS transpose -> full-line stores ----
    #pragma unroll
    for (int nt = 0; nt < 8; ++nt) {
        const int col = nt * 16 + l_lo;
        #pragma unroll
        for (int r = 0; r < 4; ++r) {
            const int row = l_hi * 4 + r;
            float v = acc[nt][r] + breg[nt];
            Fw[row * 128 + (col ^ ((row & 7) << 2))] = v > 0.f ? v : 0.f;
        }
    }
    float* dst = out + (size_t)tile * 2048;
    #pragma unroll
    for (int it = 0; it < 8; ++it) {
        const int f = it * 256 + lane * 4;
        const int r = f >> 7, c = f & 127;
        float4 v = *(const float4*)(Fw + r * 128 + (c ^ ((r & 7) << 2)));
        *(float4*)(dst + f) = v;
    }
}

// ---------- safety fallback (tiny ws / tail nodes) ----------
__global__ void k_naive(const int* __restrict__ node_ids, const int* __restrict__ nbr_idx,
                        const float* __restrict__ nbr_dist, const float* __restrict__ emb,
                        const float* __restrict__ dt, const float* __restrict__ Ws,
                        const float* __restrict__ Wn, const float* __restrict__ bias,
                        float* __restrict__ out, int base) {
    __shared__ float h[128], ag[128];
    const int nd = base + blockIdx.x;
    const int t = threadIdx.x;
    const int nid = node_ids[nd];
    float hv = emb[(size_t)nid * 128 + t];
    float a = 0.f;
    for (int k = 0; k < KNBR; ++k) {
        int sn = node_ids[nbr_idx[(size_t)nd * KNBR + k]];
        int bkt = (int)bucket_of(nbr_dist[(size_t)nd * KNBR + k]);
        a += emb[(size_t)sn * 128 + t] + dt[bkt * 128 + t];
    }
    h[t] = hv; ag[t] = a * 0.0625f;
    __syncthreads();
    float s = bias[t];
    for (int d = 0; d < 128; ++d) s += h[d] * Ws[d * 128 + t] + ag[d] * Wn[d * 128 + t];
    out[(size_t)nd * 128 + t] = s > 0.f ? s : 0.f;
}

extern "C" void kernel_launch(void* const* d_in, const int* in_sizes, int n_in,
                              void* d_out, int out_size, void* d_ws, size_t ws_size,
                              hipStream_t stream) {
    const int* node_ids   = (const int*)d_in[0];
    const int* nbr_idx    = (const int*)d_in[1];
    const float* nbr_dist = (const float*)d_in[2];
    const float* emb      = (const float*)d_in[3];
    const float* dist_tab = (const float*)d_in[4];
    const float* Ws       = (const float*)d_in[5];
    const float* Wn       = (const float*)d_in[6];
    const float* bias     = (const float*)d_in[7];
    float* out = (float*)d_out;
    const int n = in_sizes[0];
    const int in_dim = in_sizes[3] / 128;

    const size_t offEbf = 65536;               // after 64KB packed-W
    const size_t offE8  = offEbf + (size_t)in_dim * 256;
    const size_t needT  = offE8 + (size_t)in_dim * 128;

    if (ws_size < needT) {
        if (n > 0)
            k_naive<<<n, 128, 0, stream>>>(node_ids, nbr_idx, nbr_dist, emb, dist_tab, Ws, Wn, bias, out, 0);
        return;
    }
    uint16_t* Bp   = (uint16_t*)d_ws;
    uint32_t* ebf  = (uint32_t*)((char*)d_ws + offEbf);
    uint32_t* e8   = (uint32_t*)((char*)d_ws + offE8);

    k_prep<<<2176, 256, 0, stream>>>(emb, ebf, e8, in_dim * 32, Ws, Wn, Bp);

    const int ntiles = n >> 4;
    const int rem = n & 15;

    if (ntiles > 0) {
        const int nblocks = (ntiles + 3) >> 2;
        k_fused<<<nblocks, 256, 0, stream>>>(node_ids, nbr_idx, nbr_dist, ebf, (const uint16_t*)e8,
                                             dist_tab, bias, (const uint32_t*)Bp, out, ntiles);
    }
    if (rem > 0)
        k_naive<<<rem, 128, 0, stream>>>(node_ids, nbr_idx, nbr_dist, emb, dist_tab, Ws, Wn, bias, out, ntiles << 4);
}

// Round 13
// 82.862 us; speedup vs baseline: 2.9656x; 1.1347x over previous
//
#include <hip/hip_runtime.h>
#include <stdint.h>

#define KNBR 16

typedef float f32x4 __attribute__((ext_vector_type(4)));
typedef float f32x2 __attribute__((ext_vector_type(2)));
typedef __bf16 bf16x8 __attribute__((ext_vector_type(8)));

union ABFrag { uint4 u; bf16x8 v; };

__device__ __forceinline__ uint32_t bf16_rne(float x) {
    uint32_t u = __float_as_uint(x);
    return (u + 0x7fffu + ((u >> 16) & 1u)) >> 16;
}

// searchsorted(BOUNDARIES=[1,2,4,8,16,32,64,128], d) = clamp(exp + (mant!=0), 0, 8)
__device__ __forceinline__ uint32_t bucket_of(float d) {
    uint32_t u = __float_as_uint(d);
    int e = (int)((u >> 23) & 0xff) - 127;
    int b = e + ((u & 0x7fffffu) != 0 ? 1 : 0);
    return (uint32_t)min(max(b, 0), 8);
}

#define GLD(gsrc, ldst)                                                          \
    __builtin_amdgcn_global_load_lds(                                            \
        (const __attribute__((address_space(1))) void*)(gsrc),                   \
        (__attribute__((address_space(3))) void*)(ldst), 4, 0, 0)

// ---------- prep (one dispatch): cvt tables + pack W ----------
__global__ void k_prep(const float* __restrict__ src, uint32_t* __restrict__ ebf,
                       uint32_t* __restrict__ e8, int n_dwords,
                       const float* __restrict__ Ws, const float* __restrict__ Wn,
                       uint16_t* __restrict__ Bp) {
    if (blockIdx.x < 2048) {
        int i = blockIdx.x * blockDim.x + threadIdx.x;
        int stride = 2048 * blockDim.x;
        for (; i < n_dwords; i += stride) {
            float4 v = ((const float4*)src)[i];
            ebf[2 * i]     = bf16_rne(v.x) | (bf16_rne(v.y) << 16);
            ebf[2 * i + 1] = bf16_rne(v.z) | (bf16_rne(v.w) << 16);
            uint32_t p = 0;
            p = __builtin_amdgcn_cvt_pk_fp8_f32(v.x, v.y, p, false);
            p = __builtin_amdgcn_cvt_pk_fp8_f32(v.z, v.w, p, true);
            e8[i] = p;
        }
    } else {
        int o = (blockIdx.x - 2048) * blockDim.x + threadIdx.x;
        if (o >= 8 * 8 * 64 * 8) return;
        int i = o & 7, lane = (o >> 3) & 63, nt = (o >> 9) & 7, ks = o >> 12;
        int r = ks * 32 + (lane >> 4) * 8 + i;
        int c = nt * 16 + (lane & 15);
        float v = (r < 128) ? Ws[r * 128 + c] : Wn[(r - 128) * 128 + c];
        Bp[o] = (uint16_t)bf16_rne(v);
    }
}

// ---------- fused: half-tile (8 nodes) per wave, gl_lds pipeline, 16 waves/CU ----------
// Per-wave LDS (dwords): base w*2560 -> A [0,1024) + stage [1024, 1024+3*512). 40KB/block.
__global__ __launch_bounds__(256, 4) void k_fused(
    const int* __restrict__ node_ids, const int* __restrict__ nbr_idx,
    const float* __restrict__ nbr_dist,
    const uint32_t* __restrict__ emb_bf, const uint16_t* __restrict__ emb8,
    const float* __restrict__ dist_table, const float* __restrict__ bias,
    const uint32_t* __restrict__ Bp, float* __restrict__ out, int nht)
{
    __shared__ uint32_t L[4 * 2560];   // 40 KB

    const int lane = threadIdx.x & 63;
    const int w = threadIdx.x >> 6;
    const int l_hi = lane >> 4;
    const int l_lo = lane & 15;
    uint32_t* Aw = L + w * 2560;
    uint32_t* Sw = Aw + 1024;
    float* Fw = (float*)Aw;

    const int ht = blockIdx.x * 4 + w;     // half-tile: nodes [ht*8, ht*8+8)
    if (ht >= nht) return;

    // dist table + bias in regs
    float2 dreg[9];
    #pragma unroll
    for (int b = 0; b < 9; ++b)
        dreg[b] = *(const float2*)(dist_table + b * 128 + 2 * lane);
    float breg[8];
    #pragma unroll
    for (int nt = 0; nt < 8; ++nt) breg[nt] = bias[nt * 16 + l_lo];

    // ---- phase A: translate 128 neighbor ids (2 per lane) ----
    int2 nb = *(const int2*)(nbr_idx + (size_t)ht * 128 + lane * 2);
    float2 dd = *(const float2*)(nbr_dist + (size_t)ht * 128 + lane * 2);
    uint32_t ea[2];
    ea[0] = ((uint32_t)node_ids[nb.x] & 0xFFFFFFu) | (bucket_of(dd.x) << 24);
    ea[1] = ((uint32_t)node_ids[nb.y] & 0xFFFFFFu) | (bucket_of(dd.y) << 24);
    uint32_t selfv = (uint32_t)node_ids[(size_t)ht * 8 + (lane & 7)];

    // neighbor k of node j lives at lane 8*j + (k>>1), component k&1

    // ---- ISSUE(j): 1 self gl_lds (pre-swizzled src) + 8 neighbor-pair gl_lds ----
#define ISSUE(J) do {                                                                     \
        const int sw_ = ((J) & 7) << 2;                                                   \
        const uint32_t sid_ = (uint32_t)__builtin_amdgcn_readlane((int)selfv, (J));       \
        GLD(emb_bf + (size_t)sid_ * 64 + (lane ^ sw_), Aw + (J) * 128);                   \
        uint32_t* sb_ = Sw + ((J) % 3) * 512;                                             \
        _Pragma("unroll")                                                                 \
        for (int m = 0; m < 8; ++m) {                                                     \
            const int L_ = 8 * (J) + m;                                                   \
            const uint32_t s0_ = (uint32_t)__builtin_amdgcn_readlane((int)ea[0], L_) & 0xFFFFFFu; \
            const uint32_t s1_ = (uint32_t)__builtin_amdgcn_readlane((int)ea[1], L_) & 0xFFFFFFu; \
            const uint32_t sel_ = (lane < 32) ? s0_ : s1_;                                \
            GLD((const uint8_t*)emb8 + (size_t)sel_ * 128 + (lane & 31) * 4, sb_ + m * 64); \
        }                                                                                 \
    } while (0)

    // ---- CONSUME(j, VM): counted vmcnt wait, LDS consume + agg write ----
#define CONSUME(J, VM) do {                                                               \
        asm volatile("s_waitcnt vmcnt(" #VM ")" ::: "memory");                            \
        const uint16_t* st_ = (const uint16_t*)(Sw + ((J) % 3) * 512);                    \
        float ax = 0.f, ay = 0.f;                                                         \
        uint64_t c_ = 0;                                                                  \
        _Pragma("unroll")                                                                 \
        for (int k = 0; k < KNBR; ++k) {                                                  \
            const uint32_t ew_ = (uint32_t)__builtin_amdgcn_readlane((int)ea[k & 1], 8 * (J) + (k >> 1)); \
            c_ += 1ull << (5 * (ew_ >> 24));                                              \
            const uint32_t pv_ = (uint32_t)st_[k * 64 + lane];                            \
            f32x2 d_ = __builtin_amdgcn_cvt_pk_f32_fp8(pv_, false);                       \
            ax += d_.x; ay += d_.y;                                                       \
        }                                                                                 \
        _Pragma("unroll")                                                                 \
        for (int b = 0; b < 9; ++b) {                                                     \
            const float fb_ = (float)(uint32_t)((c_ >> (5 * b)) & 31u);                   \
            ax += fb_ * dreg[b].x; ay += fb_ * dreg[b].y;                                 \
        }                                                                                 \
        ax *= 0.0625f; ay *= 0.0625f;                                                     \
        const int sw_ = ((J) & 7) << 2;                                                   \
        Aw[(J) * 128 + (64 + (lane ^ sw_))] = bf16_rne(ax) | (bf16_rne(ay) << 16);        \
        __builtin_amdgcn_sched_barrier(0);                                                \
    } while (0)

    // ---- D=3-slot pipeline over the 8 nodes (lookahead 2 nodes = vmcnt 18) ----
    ISSUE(0); ISSUE(1); ISSUE(2);
    CONSUME(0, 18);  ISSUE(3);
    CONSUME(1, 18);  ISSUE(4);
    CONSUME(2, 18);  ISSUE(5);
    CONSUME(3, 18);  ISSUE(6);
    CONSUME(4, 18);  ISSUE(7);
    CONSUME(5, 18);
    CONSUME(6, 9);
    CONSUME(7, 0);
#undef ISSUE
#undef CONSUME

    asm volatile("s_waitcnt vmcnt(0) lgkmcnt(0)" ::: "memory");
    __builtin_amdgcn_sched_barrier(0);

    // ---- MFMA: 16x128, K=256 (rows 8..15 are garbage, never stored) ----
    f32x4 acc[8];
    #pragma unroll
    for (int t = 0; t < 8; ++t) acc[t] = (f32x4){0.f, 0.f, 0.f, 0.f};
    #pragma unroll
    for (int ks = 0; ks < 8; ++ks) {
        ABFrag a;   // A[row=l_lo][k = ks*32 + l_hi*8 + 0..7]
        a.u = *(const uint4*)(Aw + l_lo * 128 + ((ks * 16 + l_hi * 4) ^ ((l_lo & 7) << 2)));
        #pragma unroll
        for (int nt = 0; nt < 8; ++nt) {
            ABFrag b;   // packed weights, L2-hot
            b.u = ((const uint4*)Bp)[(ks * 8 + nt) * 64 + lane];
            acc[nt] = __builtin_amdgcn_mfma_f32_16x16x32_bf16(a.v, b.v, acc[nt], 0, 0, 0);
        }
    }

    // ---- epilogue: rows 0..7 only -> swizzled F in A region -> full-line stores ----
    #pragma unroll
    for (int nt = 0; nt < 8; ++nt) {
        const int col = nt * 16 + l_lo;
        #pragma unroll
        for (int r = 0; r < 4; ++r) {
            const int row = l_hi * 4 + r;
            if (row < 8) {
                float v = acc[nt][r] + breg[nt];
                Fw[row * 128 + (col ^ ((row & 7) << 2))] = v > 0.f ? v : 0.f;
            }
        }
    }
    float* dst = out + (size_t)ht * 1024;
    #pragma unroll
    for (int it = 0; it < 4; ++it) {
        const int f = it * 256 + lane * 4;
        const int r = f >> 7, c = f & 127;
        float4 v = *(const float4*)(Fw + r * 128 + (c ^ ((r & 7) << 2)));
        *(float4*)(dst + f) = v;
    }
}

// ---------- safety fallback (tiny ws / tail nodes) ----------
__global__ void k_naive(const int* __restrict__ node_ids, const int* __restrict__ nbr_idx,
                        const float* __restrict__ nbr_dist, const float* __restrict__ emb,
                        const float* __restrict__ dt, const float* __restrict__ Ws,
                        const float* __restrict__ Wn, const float* __restrict__ bias,
                        float* __restrict__ out, int base) {
    __shared__ float h[128], ag[128];
    const int nd = base + blockIdx.x;
    const int t = threadIdx.x;
    const int nid = node_ids[nd];
    float hv = emb[(size_t)nid * 128 + t];
    float a = 0.f;
    for (int k = 0; k < KNBR; ++k) {
        int sn = node_ids[nbr_idx[(size_t)nd * KNBR + k]];
        int bkt = (int)bucket_of(nbr_dist[(size_t)nd * KNBR + k]);
        a += emb[(size_t)sn * 128 + t] + dt[bkt * 128 + t];
    }
    h[t] = hv; ag[t] = a * 0.0625f;
    __syncthreads();
    float s = bias[t];
    for (int d = 0; d < 128; ++d) s += h[d] * Ws[d * 128 + t] + ag[d] * Wn[d * 128 + t];
    out[(size_t)nd * 128 + t] = s > 0.f ? s : 0.f;
}

extern "C" void kernel_launch(void* const* d_in, const int* in_sizes, int n_in,
                              void* d_out, int out_size, void* d_ws, size_t ws_size,
                              hipStream_t stream) {
    const int* node_ids   = (const int*)d_in[0];
    const int* nbr_idx    = (const int*)d_in[1];
    const float* nbr_dist = (const float*)d_in[2];
    const float* emb      = (const float*)d_in[3];
    const float* dist_tab = (const float*)d_in[4];
    const float* Ws       = (const float*)d_in[5];
    const float* Wn       = (const float*)d_in[6];
    const float* bias     = (const float*)d_in[7];
    float* out = (float*)d_out;
    const int n = in_sizes[0];
    const int in_dim = in_sizes[3] / 128;

    const size_t offEbf = 65536;               // after 64KB packed-W
    const size_t offE8  = offEbf + (size_t)in_dim * 256;
    const size_t needT  = offE8 + (size_t)in_dim * 128;

    if (ws_size < needT) {
        if (n > 0)
            k_naive<<<n, 128, 0, stream>>>(node_ids, nbr_idx, nbr_dist, emb, dist_tab, Ws, Wn, bias, out, 0);
        return;
    }
    uint16_t* Bp   = (uint16_t*)d_ws;
    uint32_t* ebf  = (uint32_t*)((char*)d_ws + offEbf);
    uint32_t* e8   = (uint32_t*)((char*)d_ws + offE8);

    k_prep<<<2176, 256, 0, stream>>>(emb, ebf, e8, in_dim * 32, Ws, Wn, Bp);

    const int nht = n >> 3;
    const int rem = n & 7;

    if (nht > 0) {
        const int nblocks = (nht + 3) >> 2;
        k_fused<<<nblocks, 256, 0, stream>>>(node_ids, nbr_idx, nbr_dist, ebf, (const uint16_t*)e8,
                                             dist_tab, bias, (const uint32_t*)Bp, out, nht);
    }
    if (rem > 0)
        k_naive<<<rem, 128, 0, stream>>>(node_ids, nbr_idx, nbr_dist, emb, dist_tab, Ws, Wn, bias, out, nht << 3);
}

// Round 14
// 82.471 us; speedup vs baseline: 2.9797x; 1.0047x over previous
//
#include <hip/hip_runtime.h>
#include <stdint.h>

#define KNBR 16

typedef float f32x4 __attribute__((ext_vector_type(4)));
typedef float f32x2 __attribute__((ext_vector_type(2)));
typedef __bf16 bf16x8 __attribute__((ext_vector_type(8)));

union ABFrag { uint4 u; bf16x8 v; };

__device__ __forceinline__ uint32_t bf16_rne(float x) {
    uint32_t u = __float_as_uint(x);
    return (u + 0x7fffu + ((u >> 16) & 1u)) >> 16;
}

// searchsorted(BOUNDARIES=[1,2,4,8,16,32,64,128], d) = clamp(exp + (mant!=0), 0, 8)
__device__ __forceinline__ uint32_t bucket_of(float d) {
    uint32_t u = __float_as_uint(d);
    int e = (int)((u >> 23) & 0xff) - 127;
    int b = e + ((u & 0x7fffffu) != 0 ? 1 : 0);
    return (uint32_t)min(max(b, 0), 8);
}

#define GLD(gsrc, ldst)                                                          \
    __builtin_amdgcn_global_load_lds(                                            \
        (const __attribute__((address_space(1))) void*)(gsrc),                   \
        (__attribute__((address_space(3))) void*)(ldst), 4, 0, 0)

// ---------- prep (one dispatch): cvt tables + pack W ----------
__global__ void k_prep(const float* __restrict__ src, uint32_t* __restrict__ ebf,
                       uint32_t* __restrict__ e8, int n_dwords,
                       const float* __restrict__ Ws, const float* __restrict__ Wn,
                       uint16_t* __restrict__ Bp) {
    if (blockIdx.x < 2048) {
        int i = blockIdx.x * blockDim.x + threadIdx.x;
        int stride = 2048 * blockDim.x;
        for (; i < n_dwords; i += stride) {
            float4 v = ((const float4*)src)[i];
            ebf[2 * i]     = bf16_rne(v.x) | (bf16_rne(v.y) << 16);
            ebf[2 * i + 1] = bf16_rne(v.z) | (bf16_rne(v.w) << 16);
            uint32_t p = 0;
            p = __builtin_amdgcn_cvt_pk_fp8_f32(v.x, v.y, p, false);
            p = __builtin_amdgcn_cvt_pk_fp8_f32(v.z, v.w, p, true);
            e8[i] = p;
        }
    } else {
        int o = (blockIdx.x - 2048) * blockDim.x + threadIdx.x;
        if (o >= 8 * 8 * 64 * 8) return;
        int i = o & 7, lane = (o >> 3) & 63, nt = (o >> 9) & 7, ks = o >> 12;
        int r = ks * 32 + (lane >> 4) * 8 + i;
        int c = nt * 16 + (lane & 15);
        float v = (r < 128) ? Ws[r * 128 + c] : Wn[(r - 128) * 128 + c];
        Bp[o] = (uint16_t)bf16_rne(v);
    }
}

// ---------- fused: half-tile (8 nodes)/wave, D=2 gl_lds pipeline, 20 waves/CU ----------
// Per-wave LDS (dwords): A [0,1024) + stage [1024, 1024+2*512) = 8KB. Block 32KB -> 5 blocks/CU.
__global__ __launch_bounds__(256, 5) void k_fused(
    const int* __restrict__ node_ids, const int* __restrict__ nbr_idx,
    const float* __restrict__ nbr_dist,
    const uint32_t* __restrict__ emb_bf, const uint16_t* __restrict__ emb8,
    const float* __restrict__ dist_table, const float* __restrict__ bias,
    const uint32_t* __restrict__ Bp, float* __restrict__ out, int nht)
{
    __shared__ uint32_t L[4 * 2048];   // 32 KB

    const int lane = threadIdx.x & 63;
    const int w = threadIdx.x >> 6;
    const int l_hi = lane >> 4;
    const int l_lo = lane & 15;
    uint32_t* Aw = L + w * 2048;
    uint32_t* Sw = Aw + 1024;
    float* Fw = (float*)Aw;

    const int ht = blockIdx.x * 4 + w;     // half-tile: nodes [ht*8, ht*8+8)
    if (ht >= nht) return;

    // dist table + bias in regs (f32x2 for packed math)
    f32x2 dreg[9];
    #pragma unroll
    for (int b = 0; b < 9; ++b) {
        float2 t = *(const float2*)(dist_table + b * 128 + 2 * lane);
        dreg[b] = (f32x2){t.x, t.y};
    }
    float breg[8];
    #pragma unroll
    for (int nt = 0; nt < 8; ++nt) breg[nt] = bias[nt * 16 + l_lo];

    // ---- phase A: translate 128 neighbor ids (2 per lane) ----
    int2 nb = *(const int2*)(nbr_idx + (size_t)ht * 128 + lane * 2);
    float2 dd = *(const float2*)(nbr_dist + (size_t)ht * 128 + lane * 2);
    uint32_t ea[2];
    ea[0] = ((uint32_t)node_ids[nb.x] & 0xFFFFFFu) | (bucket_of(dd.x) << 24);
    ea[1] = ((uint32_t)node_ids[nb.y] & 0xFFFFFFu) | (bucket_of(dd.y) << 24);
    uint32_t selfv = (uint32_t)node_ids[(size_t)ht * 8 + (lane & 7)];

    // neighbor k of node j lives at lane 8*j + (k>>1), component k&1

    // ---- ISSUE(j): 1 self gl_lds (pre-swizzled src) + 8 neighbor-pair gl_lds ----
#define ISSUE(J) do {                                                                     \
        const int sw_ = ((J) & 7) << 2;                                                   \
        const uint32_t sid_ = (uint32_t)__builtin_amdgcn_readlane((int)selfv, (J));       \
        GLD(emb_bf + (size_t)sid_ * 64 + (lane ^ sw_), Aw + (J) * 128);                   \
        uint32_t* sb_ = Sw + ((J) & 1) * 512;                                             \
        _Pragma("unroll")                                                                 \
        for (int m = 0; m < 8; ++m) {                                                     \
            const int L_ = 8 * (J) + m;                                                   \
            const uint32_t s0_ = (uint32_t)__builtin_amdgcn_readlane((int)ea[0], L_) & 0xFFFFFFu; \
            const uint32_t s1_ = (uint32_t)__builtin_amdgcn_readlane((int)ea[1], L_) & 0xFFFFFFu; \
            const uint32_t sel_ = (lane < 32) ? s0_ : s1_;                                \
            GLD((const uint8_t*)emb8 + (size_t)sel_ * 128 + (lane & 31) * 4, sb_ + m * 64); \
        }                                                                                 \
    } while (0)

    // ---- CONSUME(j, VM): counted vmcnt wait, packed-f32 consume + agg write ----
#define CONSUME(J, VM) do {                                                               \
        asm volatile("s_waitcnt vmcnt(" #VM ")" ::: "memory");                            \
        const uint16_t* st_ = (const uint16_t*)(Sw + ((J) & 1) * 512);                    \
        f32x2 s_ = (f32x2){0.f, 0.f};                                                     \
        uint64_t c_ = 0;                                                                  \
        _Pragma("unroll")                                                                 \
        for (int k = 0; k < KNBR; ++k) {                                                  \
            const uint32_t ew_ = (uint32_t)__builtin_amdgcn_readlane((int)ea[k & 1], 8 * (J) + (k >> 1)); \
            c_ += 1ull << (5 * (ew_ >> 24));                                              \
            const uint32_t pv_ = (uint32_t)st_[k * 64 + lane];                            \
            s_ += __builtin_amdgcn_cvt_pk_f32_fp8(pv_, false);                            \
        }                                                                                 \
        _Pragma("unroll")                                                                 \
        for (int b = 0; b < 9; ++b) {                                                     \
            const float fb_ = (float)(uint32_t)((c_ >> (5 * b)) & 31u);                   \
            s_ += (f32x2){fb_, fb_} * dreg[b];                                            \
        }                                                                                 \
        s_ *= 0.0625f;                                                                    \
        const int sw_ = ((J) & 7) << 2;                                                   \
        Aw[(J) * 128 + (64 + (lane ^ sw_))] = bf16_rne(s_.x) | (bf16_rne(s_.y) << 16);    \
        __builtin_amdgcn_sched_barrier(0);                                                \
    } while (0)

    // ---- D=2-slot pipeline over the 8 nodes (lookahead 1 node = vmcnt 9) ----
    ISSUE(0); ISSUE(1);
    CONSUME(0, 9);  ISSUE(2);
    CONSUME(1, 9);  ISSUE(3);
    CONSUME(2, 9);  ISSUE(4);
    CONSUME(3, 9);  ISSUE(5);
    CONSUME(4, 9);  ISSUE(6);
    CONSUME(5, 9);  ISSUE(7);
    CONSUME(6, 9);
    CONSUME(7, 0);
#undef ISSUE
#undef CONSUME

    asm volatile("s_waitcnt vmcnt(0) lgkmcnt(0)" ::: "memory");
    __builtin_amdgcn_sched_barrier(0);

    // ---- MFMA: 16x128, K=256 (rows 8..15 are garbage, never stored) ----
    f32x4 acc[8];
    #pragma unroll
    for (int t = 0; t < 8; ++t) acc[t] = (f32x4){0.f, 0.f, 0.f, 0.f};
    #pragma unroll
    for (int ks = 0; ks < 8; ++ks) {
        ABFrag a;   // A[row=l_lo][k = ks*32 + l_hi*8 + 0..7]
        a.u = *(const uint4*)(Aw + l_lo * 128 + ((ks * 16 + l_hi * 4) ^ ((l_lo & 7) << 2)));
        #pragma unroll
        for (int nt = 0; nt < 8; ++nt) {
            ABFrag b;   // packed weights, L2-hot
            b.u = ((const uint4*)Bp)[(ks * 8 + nt) * 64 + lane];
            acc[nt] = __builtin_amdgcn_mfma_f32_16x16x32_bf16(a.v, b.v, acc[nt], 0, 0, 0);
        }
    }

    // ---- epilogue: rows 0..7 only -> swizzled F in A region -> full-line stores ----
    #pragma unroll
    for (int nt = 0; nt < 8; ++nt) {
        const int col = nt * 16 + l_lo;
        #pragma unroll
        for (int r = 0; r < 4; ++r) {
            const int row = l_hi * 4 + r;
            if (row < 8) {
                float v = acc[nt][r] + breg[nt];
                Fw[row * 128 + (col ^ ((row & 7) << 2))] = v > 0.f ? v : 0.f;
            }
        }
    }
    float* dst = out + (size_t)ht * 1024;
    #pragma unroll
    for (int it = 0; it < 4; ++it) {
        const int f = it * 256 + lane * 4;
        const int r = f >> 7, c = f & 127;
        float4 v = *(const float4*)(Fw + r * 128 + (c ^ ((r & 7) << 2)));
        *(float4*)(dst + f) = v;
    }
}

// ---------- safety fallback (tiny ws / tail nodes) ----------
__global__ void k_naive(const int* __restrict__ node_ids, const int* __restrict__ nbr_idx,
                        const float* __restrict__ nbr_dist, const float* __restrict__ emb,
                        const float* __restrict__ dt, const float* __restrict__ Ws,
                        const float* __restrict__ Wn, const float* __restrict__ bias,
                        float* __restrict__ out, int base) {
    __shared__ float h[128], ag[128];
    const int nd = base + blockIdx.x;
    const int t = threadIdx.x;
    const int nid = node_ids[nd];
    float hv = emb[(size_t)nid * 128 + t];
    float a = 0.f;
    for (int k = 0; k < KNBR; ++k) {
        int sn = node_ids[nbr_idx[(size_t)nd * KNBR + k]];
        int bkt = (int)bucket_of(nbr_dist[(size_t)nd * KNBR + k]);
        a += emb[(size_t)sn * 128 + t] + dt[bkt * 128 + t];
    }
    h[t] = hv; ag[t] = a * 0.0625f;
    __syncthreads();
    float s = bias[t];
    for (int d = 0; d < 128; ++d) s += h[d] * Ws[d * 128 + t] + ag[d] * Wn[d * 128 + t];
    out[(size_t)nd * 128 + t] = s > 0.f ? s : 0.f;
}

extern "C" void kernel_launch(void* const* d_in, const int* in_sizes, int n_in,
                              void* d_out, int out_size, void* d_ws, size_t ws_size,
                              hipStream_t stream) {
    const int* node_ids   = (const int*)d_in[0];
    const int* nbr_idx    = (const int*)d_in[1];
    const float* nbr_dist = (const float*)d_in[2];
    const float* emb      = (const float*)d_in[3];
    const float* dist_tab = (const float*)d_in[4];
    const float* Ws       = (const float*)d_in[5];
    const float* Wn       = (const float*)d_in[6];
    const float* bias     = (const float*)d_in[7];
    float* out = (float*)d_out;
    const int n = in_sizes[0];
    const int in_dim = in_sizes[3] / 128;

    const size_t offEbf = 65536;               // after 64KB packed-W
    const size_t offE8  = offEbf + (size_t)in_dim * 256;
    const size_t needT  = offE8 + (size_t)in_dim * 128;

    if (ws_size < needT) {
        if (n > 0)
            k_naive<<<n, 128, 0, stream>>>(node_ids, nbr_idx, nbr_dist, emb, dist_tab, Ws, Wn, bias, out, 0);
        return;
    }
    uint16_t* Bp   = (uint16_t*)d_ws;
    uint32_t* ebf  = (uint32_t*)((char*)d_ws + offEbf);
    uint32_t* e8   = (uint32_t*)((char*)d_ws + offE8);

    k_prep<<<2176, 256, 0, stream>>>(emb, ebf, e8, in_dim * 32, Ws, Wn, Bp);

    const int nht = n >> 3;
    const int rem = n & 7;

    if (nht > 0) {
        const int nblocks = (nht + 3) >> 2;
        k_fused<<<nblocks, 256, 0, stream>>>(node_ids, nbr_idx, nbr_dist, ebf, (const uint16_t*)e8,
                                             dist_tab, bias, (const uint32_t*)Bp, out, nht);
    }
    if (rem > 0)
        k_naive<<<rem, 128, 0, stream>>>(node_ids, nbr_idx, nbr_dist, emb, dist_tab, Ws, Wn, bias, out, nht << 3);
}